// Round 1
// baseline (151.173 us; speedup 1.0000x reference)
//
#include <hip/hip_runtime.h>

// ---------------------------------------------------------------------------
// MoE with adaptive gate, B=8192 D=2048 E=8 H=128, fp32 in/out, bf16 MFMA core
// ---------------------------------------------------------------------------

typedef __attribute__((ext_vector_type(8))) short short8;   // 8 bf16 (4 VGPRs)
typedef __attribute__((ext_vector_type(4))) float f32x4;    // MFMA C/D

#define B_SZ 8192
#define D_SZ 2048
#define E_SZ 8
#define H_SZ 128
#define TILE_ELEMS 8192   // frag-ready tile: 128 rows x 64 k, elem = kg*1024 + p*8 + j

__device__ __forceinline__ short f2bf(float f) {
  unsigned u = __builtin_bit_cast(unsigned, f);
  unsigned r = (u + 0x7fffu + ((u >> 16) & 1u)) >> 16;   // RNE
  return (short)r;
}

__device__ __forceinline__ float silu_f(float v) {
  return v / (1.f + __expf(-v));
}

__device__ __forceinline__ void gload_lds16(const void* g, void* l) {
  __builtin_amdgcn_global_load_lds(
      (const __attribute__((address_space(1))) void*)g,
      (__attribute__((address_space(3))) void*)l,
      16, 0, 0);
}

// ---------------------------------------------------------------------------
// Core: 128x128 tile, 4 waves (2x2), BK=64, double-buffered LDS,
// one barrier per K-step.  A and B both in frag-ready layout:
// tile (kt) at base + kt*8192; within tile elem = kg*1024 + p*8 + j,
// logical k = kt*64 + kg*8 + j, p = row (A) / col (B).
// ---------------------------------------------------------------------------
template<int NKT>
__device__ __forceinline__ void gemm_core(const short* __restrict__ Ab,
                                          const short* __restrict__ Bb,
                                          short* lds, f32x4 acc[4][4])
{
  const int tid  = threadIdx.x;
  const int lane = tid & 63;
  const int wid  = tid >> 6;
  const int wr = wid >> 1, wc = wid & 1;
  const int lm = lane & 15, lk = lane >> 4;
  const int wbase = tid & ~63;
  short* As = lds;                  // [2][8192]
  short* Bs = lds + 2 * TILE_ELEMS; // [2][8192]

  // prologue: stage kt=0 into buffer 0
  #pragma unroll
  for (int q = 0; q < 4; ++q) {
    gload_lds16(Ab + (q*256 + tid)*8, As + (q*256 + wbase)*8);
    gload_lds16(Bb + (q*256 + tid)*8, Bs + (q*256 + wbase)*8);
  }
  __syncthreads();   // compiler drains vmcnt(0) before s_barrier

  for (int kt = 0; kt < NKT; ++kt) {
    const int cur = kt & 1;
    if (kt + 1 < NKT) {   // issue next-tile loads before compute (T3 minimum 2-phase)
      const short* ga = Ab + (size_t)(kt+1)*TILE_ELEMS;
      const short* gb = Bb + (size_t)(kt+1)*TILE_ELEMS;
      short* la = As + (cur^1)*TILE_ELEMS;
      short* lb = Bs + (cur^1)*TILE_ELEMS;
      #pragma unroll
      for (int q = 0; q < 4; ++q) {
        gload_lds16(ga + (q*256 + tid)*8, la + (q*256 + wbase)*8);
        gload_lds16(gb + (q*256 + tid)*8, lb + (q*256 + wbase)*8);
      }
    }
    const short* Ac = As + cur*TILE_ELEMS;
    const short* Bc = Bs + cur*TILE_ELEMS;
    #pragma unroll
    for (int ks = 0; ks < 2; ++ks) {
      short8 av[4], bv[4];
      #pragma unroll
      for (int f = 0; f < 4; ++f)
        av[f] = *(const short8*)(Ac + (ks*4 + lk)*1024 + (wr*64 + f*16 + lm)*8);
      #pragma unroll
      for (int f = 0; f < 4; ++f)
        bv[f] = *(const short8*)(Bc + (ks*4 + lk)*1024 + (wc*64 + f*16 + lm)*8);
      #pragma unroll
      for (int i = 0; i < 4; ++i)
        #pragma unroll
        for (int j = 0; j < 4; ++j)
          acc[i][j] = __builtin_amdgcn_mfma_f32_16x16x32_bf16(av[i], bv[j], acc[i][j], 0, 0, 0);
    }
    __syncthreads();   // staged loads drained; cur-buffer reads done
  }
}

// ---------------------------------------------------------------------------
// K0: convert x / W1 / W2 / W3 into bf16 frag-ready layouts.
// One thread per 8-element group (one short8 write, coalesced).
// ---------------------------------------------------------------------------
__global__ __launch_bounds__(256)
void k_convert(const float* __restrict__ x,  const float* __restrict__ W1,
               const float* __restrict__ W2, const float* __restrict__ W3,
               short* __restrict__ xf, short* __restrict__ w1f,
               short* __restrict__ w2f, short* __restrict__ w3f)
{
  const int gi = blockIdx.x * 256 + threadIdx.x;
  if (gi < 2097152) {                       // xf: A-FR of x [8192][2048]
    const int t = gi >> 10, r = gi & 1023;
    const int bt = t >> 5, kt = t & 31;
    const int kg = r >> 7, p = r & 127;
    const float* src = x + (size_t)(bt*128 + p)*2048 + kt*64 + kg*8;
    const float4 v0 = *(const float4*)src;
    const float4 v1 = *(const float4*)(src + 4);
    short8 o;
    o[0]=f2bf(v0.x); o[1]=f2bf(v0.y); o[2]=f2bf(v0.z); o[3]=f2bf(v0.w);
    o[4]=f2bf(v1.x); o[5]=f2bf(v1.y); o[6]=f2bf(v1.z); o[7]=f2bf(v1.w);
    *(short8*)(xf + (size_t)gi*8) = o;
  } else if (gi < 2097152 + 262144) {       // w1f: B-FR of W1[e] [2048][128]
    const int g = gi - 2097152;
    const int t = g >> 10, r = g & 1023;
    const int e = t >> 5, kt = t & 31;
    const int kg = r >> 7, p = r & 127;     // p = h (col)
    const int k0 = kt*64 + kg*8;
    short8 o;
    #pragma unroll
    for (int j = 0; j < 8; ++j)
      o[j] = f2bf(W1[(size_t)e*262144 + (size_t)(k0 + j)*128 + p]);
    *(short8*)(w1f + (size_t)g*8) = o;
  } else if (gi < 2097152 + 262144 + 16384) { // w2f: B-FR of W2[e] [128][128]
    const int g = gi - (2097152 + 262144);
    const int t = g >> 10, r = g & 1023;
    const int e = t >> 1, kt = t & 1;
    const int kg = r >> 7, p = r & 127;
    const int k0 = kt*64 + kg*8;
    short8 o;
    #pragma unroll
    for (int j = 0; j < 8; ++j)
      o[j] = f2bf(W2[(size_t)e*16384 + (size_t)(k0 + j)*128 + p]);
    *(short8*)(w2f + (size_t)g*8) = o;
  } else if (gi < 2637824) {                // w3f: B-FR of W3 flat [1024][2048]
    const int g = gi - 2375680;
    const int t = g >> 10, r = g & 1023;
    const int nt = t >> 4, kt = t & 15;
    const int kg = r >> 7, p = r & 127;     // p = local dout
    const int k0 = kt*64 + kg*8;
    short8 o;
    #pragma unroll
    for (int j = 0; j < 8; ++j) {
      const int k = k0 + j;                 // k = e*128 + h
      o[j] = f2bf(W3[(size_t)(k >> 7)*262144 + (size_t)(k & 127)*2048 + nt*128 + p]);
    }
    *(short8*)(w3f + (size_t)g*8) = o;
  }
}

// ---------------------------------------------------------------------------
// K1: gate softmax.  One wave per row, fp32 end-to-end.
// ---------------------------------------------------------------------------
__global__ __launch_bounds__(256)
void k_gate(const float* __restrict__ x, const float* __restrict__ gw,
            const float* __restrict__ gb, float* __restrict__ gates)
{
  const int wid = threadIdx.x >> 6, lane = threadIdx.x & 63;
  const int row = blockIdx.x * 4 + wid;
  const float* xr = x + (size_t)row * 2048;
  float acc[8] = {0.f,0.f,0.f,0.f,0.f,0.f,0.f,0.f};
  for (int it = 0; it < 32; ++it) {
    const int k = it*64 + lane;
    const float xv = xr[k];
    const float4 g0 = *(const float4*)(gw + (size_t)k*8);
    const float4 g1 = *(const float4*)(gw + (size_t)k*8 + 4);
    acc[0] += xv*g0.x; acc[1] += xv*g0.y; acc[2] += xv*g0.z; acc[3] += xv*g0.w;
    acc[4] += xv*g1.x; acc[5] += xv*g1.y; acc[6] += xv*g1.z; acc[7] += xv*g1.w;
  }
  #pragma unroll
  for (int e = 0; e < 8; ++e) {
    #pragma unroll
    for (int d = 1; d < 64; d <<= 1)
      acc[e] += __shfl_xor(acc[e], d, 64);
  }
  if (lane == 0) {
    float lg[8], mx = -1e30f;
    #pragma unroll
    for (int e = 0; e < 8; ++e) { lg[e] = acc[e] + gb[e]; mx = fmaxf(mx, lg[e]); }
    float s = 0.f;
    #pragma unroll
    for (int e = 0; e < 8; ++e) { lg[e] = __expf(lg[e] - mx); s += lg[e]; }
    const float inv = 1.f / s;
    #pragma unroll
    for (int e = 0; e < 8; ++e) gates[(size_t)row*8 + e] = lg[e] * inv;
  }
}

// ---------------------------------------------------------------------------
// K2: h1[e] = silu(x @ W1[e] + b1[e])  -> frag-ready bf16
// ---------------------------------------------------------------------------
__global__ __launch_bounds__(256, 2)
void k_gemm1(const short* __restrict__ xf, const short* __restrict__ w1f,
             const float* __restrict__ b1, short* __restrict__ h1f)
{
  __shared__ short lds[4 * TILE_ELEMS];
  const int bt = blockIdx.x, e = blockIdx.y;
  f32x4 acc[4][4] = {};
  gemm_core<32>(xf + (size_t)bt*32*TILE_ELEMS, w1f + (size_t)e*32*TILE_ELEMS, lds, acc);

  const int tid = threadIdx.x, lane = tid & 63, wid = tid >> 6;
  const int wr = wid >> 1, wc = wid & 1, lm = lane & 15;
  float bv[4];
  #pragma unroll
  for (int fn = 0; fn < 4; ++fn) bv[fn] = b1[e*H_SZ + wc*64 + fn*16 + lm];
  #pragma unroll
  for (int fm = 0; fm < 4; ++fm)
  #pragma unroll
  for (int i = 0; i < 4; ++i) {
    const int m = wr*64 + fm*16 + (lane>>4)*4 + i;
    #pragma unroll
    for (int fn = 0; fn < 4; ++fn) {
      const int n = wc*64 + fn*16 + lm;
      float v = silu_f(acc[fm][fn][i] + bv[fn]);
      lds[(n>>6)*TILE_ELEMS + ((n>>3)&7)*1024 + m*8 + (n&7)] = f2bf(v);
    }
  }
  __syncthreads();
  short* gout = h1f + (size_t)e*1048576 + (size_t)bt*16384;
  #pragma unroll
  for (int q = 0; q < 8; ++q) {
    const int li = q*256 + tid;
    *(short8*)(gout + li*8) = *(const short8*)(lds + li*8);
  }
}

// ---------------------------------------------------------------------------
// K3: h2g[e] = gates[:,e] * silu(h1[e] @ W2[e] + b2[e])  -> frag-ready bf16,
// written into K-slots [e*128, (e+1)*128) of the [8192][1024] activation.
// ---------------------------------------------------------------------------
__global__ __launch_bounds__(256, 2)
void k_gemm2(const short* __restrict__ h1f, const short* __restrict__ w2f,
             const float* __restrict__ b2, const float* __restrict__ gates,
             short* __restrict__ h2gf)
{
  __shared__ short lds[4 * TILE_ELEMS];
  const int bt = blockIdx.x, e = blockIdx.y;
  f32x4 acc[4][4] = {};
  gemm_core<2>(h1f + (size_t)e*1048576 + (size_t)bt*16384,
               w2f + (size_t)e*2*TILE_ELEMS, lds, acc);

  const int tid = threadIdx.x, lane = tid & 63, wid = tid >> 6;
  const int wr = wid >> 1, wc = wid & 1, lm = lane & 15;
  float bv[4];
  #pragma unroll
  for (int fn = 0; fn < 4; ++fn) bv[fn] = b2[e*H_SZ + wc*64 + fn*16 + lm];
  #pragma unroll
  for (int fm = 0; fm < 4; ++fm)
  #pragma unroll
  for (int i = 0; i < 4; ++i) {
    const int m = wr*64 + fm*16 + (lane>>4)*4 + i;
    const float g = gates[(size_t)(bt*128 + m)*8 + e];
    #pragma unroll
    for (int fn = 0; fn < 4; ++fn) {
      const int n = wc*64 + fn*16 + lm;
      float v = silu_f(acc[fm][fn][i] + bv[fn]) * g;
      lds[(n>>6)*TILE_ELEMS + ((n>>3)&7)*1024 + m*8 + (n&7)] = f2bf(v);
    }
  }
  __syncthreads();
  short* gout = h2gf + (size_t)bt*16384*8 + (size_t)e*16384;  // (bt*16 + 2e)*8192
  #pragma unroll
  for (int q = 0; q < 8; ++q) {
    const int li = q*256 + tid;
    *(short8*)(gout + li*8) = *(const short8*)(lds + li*8);
  }
}

// ---------------------------------------------------------------------------
// K4: out = h2g @ W3flat + gates @ b3   (fp32 output, direct coalesced store)
// ---------------------------------------------------------------------------
__global__ __launch_bounds__(256, 2)
void k_gemm3(const short* __restrict__ h2gf, const short* __restrict__ w3f,
             const float* __restrict__ b3, const float* __restrict__ gates,
             float* __restrict__ out)
{
  __shared__ short lds[4 * TILE_ELEMS];
  const int bt = blockIdx.x, nt = blockIdx.y;
  f32x4 acc[4][4] = {};
  gemm_core<16>(h2gf + (size_t)bt*16*TILE_ELEMS, w3f + (size_t)nt*16*TILE_ELEMS, lds, acc);

  const int tid = threadIdx.x, lane = tid & 63, wid = tid >> 6;
  const int wr = wid >> 1, wc = wid & 1, lm = lane & 15;
  float b3c[4][8];
  #pragma unroll
  for (int fn = 0; fn < 4; ++fn) {
    const int n = nt*128 + wc*64 + fn*16 + lm;
    #pragma unroll
    for (int e = 0; e < 8; ++e) b3c[fn][e] = b3[(size_t)e*D_SZ + n];
  }
  #pragma unroll
  for (int fm = 0; fm < 4; ++fm)
  #pragma unroll
  for (int i = 0; i < 4; ++i) {
    const int m = bt*128 + wr*64 + fm*16 + (lane>>4)*4 + i;
    const float4 ga = *(const float4*)(gates + (size_t)m*8);
    const float4 gbv = *(const float4*)(gates + (size_t)m*8 + 4);
    #pragma unroll
    for (int fn = 0; fn < 4; ++fn) {
      const int n = nt*128 + wc*64 + fn*16 + lm;
      const float bias = ga.x*b3c[fn][0] + ga.y*b3c[fn][1] + ga.z*b3c[fn][2] + ga.w*b3c[fn][3]
                       + gbv.x*b3c[fn][4] + gbv.y*b3c[fn][5] + gbv.z*b3c[fn][6] + gbv.w*b3c[fn][7];
      out[(size_t)m*D_SZ + n] = acc[fm][fn][i] + bias;
    }
  }
}

// ---------------------------------------------------------------------------
extern "C" void kernel_launch(void* const* d_in, const int* in_sizes, int n_in,
                              void* d_out, int out_size, void* d_ws, size_t ws_size,
                              hipStream_t stream)
{
  (void)in_sizes; (void)n_in; (void)out_size; (void)ws_size;
  const float* x  = (const float*)d_in[0];
  const float* gw = (const float*)d_in[1];
  const float* gb = (const float*)d_in[2];
  const float* W1 = (const float*)d_in[3];
  const float* b1 = (const float*)d_in[4];
  const float* W2 = (const float*)d_in[5];
  const float* b2 = (const float*)d_in[6];
  const float* W3 = (const float*)d_in[7];
  const float* b3 = (const float*)d_in[8];
  float* out = (float*)d_out;

  char* ws = (char*)d_ws;
  short* xf    = (short*)ws;  ws += (size_t)B_SZ*D_SZ*2;          // 33.5 MB
  short* w1f   = (short*)ws;  ws += (size_t)E_SZ*D_SZ*H_SZ*2;     //  4.2 MB
  short* w2f   = (short*)ws;  ws += (size_t)E_SZ*H_SZ*H_SZ*2;     //  0.26 MB
  short* w3f   = (short*)ws;  ws += (size_t)E_SZ*H_SZ*D_SZ*2;     //  4.2 MB
  float* gates = (float*)ws;  ws += (size_t)B_SZ*E_SZ*4;          //  0.26 MB
  short* h1f   = (short*)ws;  ws += (size_t)E_SZ*B_SZ*H_SZ*2;     // 33.5 MB
  short* h2gf  = (short*)ws;  ws += (size_t)B_SZ*E_SZ*H_SZ*2;     // 16.8 MB

  k_convert<<<dim3(10304), dim3(256), 0, stream>>>(x, W1, W2, W3, xf, w1f, w2f, w3f);
  k_gate   <<<dim3(2048),  dim3(256), 0, stream>>>(x, gw, gb, gates);
  k_gemm1  <<<dim3(64, 8), dim3(256), 0, stream>>>(xf, w1f, b1, h1f);
  k_gemm2  <<<dim3(64, 8), dim3(256), 0, stream>>>(h1f, w2f, b2, gates, h2gf);
  k_gemm3  <<<dim3(64, 16), dim3(256), 0, stream>>>(h2gf, w3f, b3, gates, out);
}